// Round 1
// baseline (414.694 us; speedup 1.0000x reference)
//
#include <hip/hip_runtime.h>

#define N_NODES 50000
#define D       256
#define E_EDGES 400000
#define LN_EPS  1e-5f

#define SCAN_N  (3 * N_NODES)                       // 150000
#define SCAN_B  1024
#define SCAN_NB ((SCAN_N + SCAN_B - 1) / SCAN_B)    // 147

#define NQ      (3 * E_EDGES / 4)                   // 300000 edge-quads
#define QNB     ((NQ + 255) / 256)                  // 1172
#define E_Q     (E_EDGES / 4)                       // 100000 quads/relation

#define NE8     (3 * E_EDGES / 8)                   // 150000 edge-octets
#define E_8     (E_EDGES / 8)                       // 50000 octets/relation
#define DEG_NB8 ((NE8 + 255) / 256)                 // 586

#define Z_INT4  ((SCAN_N + 4) / 4)                  // 37501 int4s (deg+flag)
#define ZNB     ((Z_INT4 + 255) / 256)              // 147

#define GB_ROWS 64
#define GEMM_NB ((N_NODES + GB_ROWS - 1) / GB_ROWS) // 782

typedef __attribute__((ext_vector_type(8))) short bf16x8;
typedef __attribute__((ext_vector_type(4))) float f32x4;
typedef __attribute__((ext_vector_type(2))) float f32x2;

__device__ __forceinline__ unsigned short f2bf(float f) {
    unsigned int x = __float_as_uint(f);
    x += 0x7fffu + ((x >> 16) & 1u);     // RNE
    return (unsigned short)(x >> 16);
}

// ---------------------------------------------------------------------------
// K1: workspace zero (deg + flag, replaces hipMemsetAsync) + Wt transpose:
//     Wt[n][k] = bf16((W0+W1+W2)[k][n] / 3)   (MFMA B^T layout)
// (softmax of size-1 tensors == 1; softmax([1,1,1]) == exactly 1/3 each)
// ---------------------------------------------------------------------------
__global__ __launch_bounds__(256) void k_zero_wt(const float* __restrict__ W0,
                                                 const float* __restrict__ W1,
                                                 const float* __restrict__ W2,
                                                 unsigned short* __restrict__ Wt,
                                                 int4* __restrict__ zb) {
    int b = blockIdx.x;
    if (b < ZNB) {
        int i = b * 256 + threadIdx.x;
        if (i < Z_INT4) zb[i] = make_int4(0, 0, 0, 0);
    } else {
        int i = (b - ZNB) * 256 + threadIdx.x;   // i = n*256 + k
        int n = i >> 8, k = i & 255;
        float v = (W0[k * D + n] + W1[k * D + n] + W2[k * D + n]) * (1.0f / 3.0f);
        Wt[i] = f2bf(v);
    }
}

// ---------------------------------------------------------------------------
// K2 "main": three independent block roles in one dispatch:
//   blocks [0, DEG_NB8):       deg count + per-edge rank (atomic returns),
//                              then last-finished deg block (atomic flag)
//                              runs the ENTIRE prefix scan (off, bsum) —
//                              its ~5us hides under the concurrent GEMM blocks.
//   blocks [DEG_NB8, +GEMM_NB): MFMA GEMM h = bf16(feat) @ Wt^T,
//                              64-row / 256-thread / 4-wave tiles (the proven
//                              32-row 2-wave structure, doubled).
// No block ever waits on a flag (last-block pattern only) -> deadlock-free.
// off = exclusive scan LOCAL to each 1024-chunk; bsum[c] = global chunk base.
// ---------------------------------------------------------------------------
__global__ __launch_bounds__(256, 3) void k_main(const int* __restrict__ dst0,
                                                 const int* __restrict__ dst1,
                                                 const int* __restrict__ dst2,
                                                 int* __restrict__ deg,
                                                 int* __restrict__ rank,
                                                 int* __restrict__ flag,
                                                 int* __restrict__ off,
                                                 int* __restrict__ bsum,
                                                 const float* __restrict__ feat,
                                                 const unsigned short* __restrict__ Wt,
                                                 unsigned short* __restrict__ h) {
    __shared__ unsigned short sA[GB_ROWS][D + 8];   // gemm path (+8 bf16 pad)
    __shared__ int csum[SCAN_NB + 1];               // scan path chunk totals
    __shared__ int sflag;

    const int b = blockIdx.x;
    const int t = threadIdx.x;

    if (b < DEG_NB8) {
        // ---- deg count + rank ----
        int q8 = b * 256 + t;                    // octet id
        if (q8 < NE8) {
            int r = q8 / E_8;
            int o = q8 - r * E_8;
            int j8 = o * 8;
            const int* dp = (r == 0) ? dst0 : (r == 1) ? dst1 : dst2;
            int4 dA = *(const int4*)(dp + j8);
            int4 dB = *(const int4*)(dp + j8 + 4);
            int base = r * N_NODES;
            int4 ra, rb;
            ra.x = atomicAdd(&deg[base + dA.x], 1);
            ra.y = atomicAdd(&deg[base + dA.y], 1);
            ra.z = atomicAdd(&deg[base + dA.z], 1);
            ra.w = atomicAdd(&deg[base + dA.w], 1);
            rb.x = atomicAdd(&deg[base + dB.x], 1);
            rb.y = atomicAdd(&deg[base + dB.y], 1);
            rb.z = atomicAdd(&deg[base + dB.z], 1);
            rb.w = atomicAdd(&deg[base + dB.w], 1);
            int q = r * E_Q + o * 2;
            *(int4*)(rank + q * 4)     = ra;
            *(int4*)(rank + q * 4 + 4) = rb;
        }
        // ---- last-finished deg block does the scan ----
        __threadfence();
        if (t == 0) sflag = (atomicAdd(flag, 1) == DEG_NB8 - 1);
        __syncthreads();
        if (!sflag) return;
        __threadfence();

        const int w = t >> 6, lane = t & 63;
        // Phase A: per-chunk local exclusive scan -> off; chunk totals -> csum
        for (int c = w; c < SCAN_NB; c += 4) {
            int base = c * SCAN_B + lane * 16;
            int4 a[4];
#pragma unroll
            for (int q = 0; q < 4; ++q)
                a[q] = *(const int4*)(deg + base + q * 4);
            int run = 0;
            int pre[16];
#pragma unroll
            for (int q = 0; q < 4; ++q) {
                pre[4 * q + 0] = run; run += a[q].x;
                pre[4 * q + 1] = run; run += a[q].y;
                pre[4 * q + 2] = run; run += a[q].z;
                pre[4 * q + 3] = run; run += a[q].w;
            }
            const int T = run;
            int x = T;
#pragma unroll
            for (int o2 = 1; o2 < 64; o2 <<= 1) {
                int y = __shfl_up(x, o2, 64);
                if (lane >= o2) x += y;
            }
            const int excl = x - T;
            if (lane == 63) csum[c] = x;         // inclusive chunk total
            if (base < SCAN_N) {                 // exact: SCAN_N % 16 == 0
#pragma unroll
                for (int q = 0; q < 4; ++q) {
                    int4 o4 = make_int4(excl + pre[4 * q + 0], excl + pre[4 * q + 1],
                                        excl + pre[4 * q + 2], excl + pre[4 * q + 3]);
                    *(int4*)(off + base + q * 4) = o4;
                }
            }
        }
        __syncthreads();
        // Phase B: scan chunk totals -> bsum (wave 0, 3 rounds of 64 w/ carry)
        if (w == 0) {
            int carry = 0;
            for (int r0 = 0; r0 < SCAN_NB; r0 += 64) {
                int c = r0 + lane;
                int v = (c < SCAN_NB) ? csum[c] : 0;
                int x = v;
#pragma unroll
                for (int o2 = 1; o2 < 64; o2 <<= 1) {
                    int y = __shfl_up(x, o2, 64);
                    if (lane >= o2) x += y;
                }
                if (c < SCAN_NB) bsum[c] = carry + x - v;
                carry += __shfl(x, 63, 64);
            }
        }
        return;
    }

    // ---- GEMM path: h_bf16 = bf16(feat) @ Wt^T ----
    const int row0 = (b - DEG_NB8) * GB_ROWS;
    const float4* feat4 = (const float4*)feat;
#pragma unroll
    for (int i = 0; i < 16; ++i) {
        int c = i * 256 + t;
        int r = c >> 6, c4 = c & 63;
        float4 v = make_float4(0.f, 0.f, 0.f, 0.f);
        if (row0 + r < N_NODES) v = feat4[(size_t)(row0 + r) * 64 + c4];
        ushort4 p;
        p.x = f2bf(v.x); p.y = f2bf(v.y); p.z = f2bf(v.z); p.w = f2bf(v.w);
        *(ushort4*)&sA[r][c4 * 4] = p;
    }
    __syncthreads();

    const int lane = t & 63;
    const int w    = t >> 6;        // 0..3
    const int lr   = lane & 15;
    const int lq   = lane >> 4;

    f32x4 acc[16];
#pragma unroll
    for (int tt = 0; tt < 16; ++tt) acc[tt] = (f32x4){0.f, 0.f, 0.f, 0.f};

    const bf16x8* WtV = (const bf16x8*)Wt;
#pragma unroll
    for (int ks = 0; ks < 8; ++ks) {
        bf16x8 bfr[16];
#pragma unroll
        for (int tt = 0; tt < 16; ++tt)
            bfr[tt] = WtV[(tt * 16 + lr) * 32 + ks * 4 + lq];
        bf16x8 af = *(const bf16x8*)&sA[w * 16 + lr][ks * 32 + lq * 8];
#pragma unroll
        for (int tt = 0; tt < 16; ++tt)
            acc[tt] = __builtin_amdgcn_mfma_f32_16x16x32_bf16(af, bfr[tt], acc[tt], 0, 0, 0);
    }

    // each wave writes only its own 16-row stripe: no cross-wave hazard
#pragma unroll
    for (int tt = 0; tt < 16; ++tt) {
#pragma unroll
        for (int j = 0; j < 4; ++j)
            sA[w * 16 + lq * 4 + j][tt * 16 + lr] = f2bf(acc[tt][j]);
    }
    __syncthreads();

#pragma unroll
    for (int i = 0; i < 8; ++i) {
        int c = i * 256 + t;
        int r = c >> 5, cc = c & 31;
        if (row0 + r < N_NODES) {
            uint4 v = *(const uint4*)&sA[r][cc * 8];
            *(uint4*)(h + (size_t)(row0 + r) * D + cc * 8) = v;
        }
    }
}

// ---------------------------------------------------------------------------
// K3: bucket fill, atomic-free: pos = off[bucket] + bsum[blk] + rank[edge].
// (R6-proven verbatim)
// ---------------------------------------------------------------------------
__global__ __launch_bounds__(256) void k_fill(const int* __restrict__ src0,
                                              const int* __restrict__ dst0,
                                              const int* __restrict__ src1,
                                              const int* __restrict__ dst1,
                                              const int* __restrict__ src2,
                                              const int* __restrict__ dst2,
                                              const int* __restrict__ off,
                                              const int* __restrict__ bsum,
                                              const int* __restrict__ rank,
                                              int* __restrict__ eidx) {
    int q = blockIdx.x * 256 + threadIdx.x;
    if (q >= NQ) return;
    int r = q / E_Q;
    int j4 = (q - r * E_Q) * 4;
    const int* sp = (r == 0) ? src0 : (r == 1) ? src1 : src2;
    const int* dp = (r == 0) ? dst0 : (r == 1) ? dst1 : dst2;
    int4 s4 = *(const int4*)(sp + j4);
    int4 d4 = *(const int4*)(dp + j4);
    int4 rk = *(const int4*)(rank + q * 4);
    int base = r * N_NODES;
    int i0 = base + d4.x, i1 = base + d4.y, i2 = base + d4.z, i3 = base + d4.w;
    int p0 = off[i0] + bsum[i0 >> 10] + rk.x;
    int p1 = off[i1] + bsum[i1 >> 10] + rk.y;
    int p2 = off[i2] + bsum[i2 >> 10] + rk.z;
    int p3 = off[i3] + bsum[i3 >> 10] + rk.w;
    eidx[p0] = s4.x;
    eidx[p1] = s4.y;
    eidx[p2] = s4.z;
    eidx[p3] = s4.w;
}

// ---------------------------------------------------------------------------
// K4: fused gather + ReLU + LayerNorm.
// One node per wave. The wave's two 32-lane halves each own ONE edge per
// 16B uint4 load (row = 32 lanes x 16B): row-load instrs halved vs uint2.
// eidx reads are wave-uniform -> readfirstlane => scalar s_load_dwordx8.
// Halves hold independent partial sums over even/odd edges of identical
// channels; combined once at the end via shfl_xor(32).
// ---------------------------------------------------------------------------
__device__ __forceinline__ void pair_acc(const uint4* __restrict__ h4, int sa, int sb,
                                         int half, int cl,
                                         f32x2& a0, f32x2& a1, f32x2& a2, f32x2& a3) {
    int su = half ? sb : sa;
    uint4 u = h4[(size_t)su * 32 + cl];
    f32x2 v;
    v.x = __uint_as_float(u.x << 16); v.y = __uint_as_float(u.x & 0xffff0000u); a0 += v;
    v.x = __uint_as_float(u.y << 16); v.y = __uint_as_float(u.y & 0xffff0000u); a1 += v;
    v.x = __uint_as_float(u.z << 16); v.y = __uint_as_float(u.z & 0xffff0000u); a2 += v;
    v.x = __uint_as_float(u.w << 16); v.y = __uint_as_float(u.w & 0xffff0000u); a3 += v;
}

__global__ __launch_bounds__(256) void k_gather(const unsigned short* __restrict__ h,
                                                const int* __restrict__ eidx,
                                                const int* __restrict__ off,
                                                const int* __restrict__ bsum,
                                                const int* __restrict__ deg,
                                                const float* __restrict__ gamma,
                                                const float* __restrict__ beta,
                                                float* __restrict__ out) {
    int node = blockIdx.x * 4 + (threadIdx.x >> 6);
    if (node >= N_NODES) return;
    const int lane = threadIdx.x & 63;
    const int half = lane >> 5;          // 0: even edges, 1: odd edges
    const int cl   = lane & 31;          // channel block: ch [cl*8, cl*8+8)
    const uint4* h4 = (const uint4*)h;

    f32x2 acc0 = (f32x2)0.f, acc1 = (f32x2)0.f, acc2 = (f32x2)0.f, acc3 = (f32x2)0.f;
#pragma unroll
    for (int r = 0; r < 3; ++r) {
        int idx = r * N_NODES + node;
        int dg = deg[idx];
        int start = off[idx] + bsum[idx >> 10];
        int end = start + dg;
        float wgt = 1.0f / (3.0f * (float)(dg > 1 ? dg : 1));
        f32x2 r0 = (f32x2)0.f, r1 = (f32x2)0.f, r2 = (f32x2)0.f, r3 = (f32x2)0.f;

        int k = start;
        for (; k + 8 <= end; k += 8) {           // 8 edges = 4 pair-loads
            int kk = __builtin_amdgcn_readfirstlane(k);
            int s0 = eidx[kk + 0], s1 = eidx[kk + 1], s2 = eidx[kk + 2], s3 = eidx[kk + 3];
            int s4 = eidx[kk + 4], s5 = eidx[kk + 5], s6 = eidx[kk + 6], s7 = eidx[kk + 7];
            pair_acc(h4, s0, s1, half, cl, r0, r1, r2, r3);
            pair_acc(h4, s2, s3, half, cl, r0, r1, r2, r3);
            pair_acc(h4, s4, s5, half, cl, r0, r1, r2, r3);
            pair_acc(h4, s6, s7, half, cl, r0, r1, r2, r3);
        }
        if (k + 4 <= end) {                      // 4 edges = 2 pair-loads
            int kk = __builtin_amdgcn_readfirstlane(k);
            int s0 = eidx[kk + 0], s1 = eidx[kk + 1], s2 = eidx[kk + 2], s3 = eidx[kk + 3];
            pair_acc(h4, s0, s1, half, cl, r0, r1, r2, r3);
            pair_acc(h4, s2, s3, half, cl, r0, r1, r2, r3);
            k += 4;
        }
        if (k + 2 <= end) {                      // 2 edges = 1 pair-load
            int kk = __builtin_amdgcn_readfirstlane(k);
            int s0 = eidx[kk + 0], s1 = eidx[kk + 1];
            pair_acc(h4, s0, s1, half, cl, r0, r1, r2, r3);
            k += 2;
        }
        if (k < end) {                           // tail edge: lower half only
            int s0 = eidx[__builtin_amdgcn_readfirstlane(k)];
            if (!half) {
                uint4 u = h4[(size_t)s0 * 32 + cl];
                f32x2 v;
                v.x = __uint_as_float(u.x << 16); v.y = __uint_as_float(u.x & 0xffff0000u); r0 += v;
                v.x = __uint_as_float(u.y << 16); v.y = __uint_as_float(u.y & 0xffff0000u); r1 += v;
                v.x = __uint_as_float(u.z << 16); v.y = __uint_as_float(u.z & 0xffff0000u); r2 += v;
                v.x = __uint_as_float(u.w << 16); v.y = __uint_as_float(u.w & 0xffff0000u); r3 += v;
            }
        }
        acc0 += r0 * wgt;
        acc1 += r1 * wgt;
        acc2 += r2 * wgt;
        acc3 += r3 * wgt;
    }

    // combine even/odd halves (both halves end up with the full sums)
    acc0.x += __shfl_xor(acc0.x, 32, 64); acc0.y += __shfl_xor(acc0.y, 32, 64);
    acc1.x += __shfl_xor(acc1.x, 32, 64); acc1.y += __shfl_xor(acc1.y, 32, 64);
    acc2.x += __shfl_xor(acc2.x, 32, 64); acc2.y += __shfl_xor(acc2.y, 32, 64);
    acc3.x += __shfl_xor(acc3.x, 32, 64); acc3.y += __shfl_xor(acc3.y, 32, 64);

    // ReLU
    acc0.x = fmaxf(acc0.x, 0.f); acc0.y = fmaxf(acc0.y, 0.f);
    acc1.x = fmaxf(acc1.x, 0.f); acc1.y = fmaxf(acc1.y, 0.f);
    acc2.x = fmaxf(acc2.x, 0.f); acc2.y = fmaxf(acc2.y, 0.f);
    acc3.x = fmaxf(acc3.x, 0.f); acc3.y = fmaxf(acc3.y, 0.f);

    // LayerNorm: each 32-lane half holds identical data; reduce within half
    float s  = acc0.x + acc0.y + acc1.x + acc1.y + acc2.x + acc2.y + acc3.x + acc3.y;
    float ss = acc0.x * acc0.x + acc0.y * acc0.y + acc1.x * acc1.x + acc1.y * acc1.y
             + acc2.x * acc2.x + acc2.y * acc2.y + acc3.x * acc3.x + acc3.y * acc3.y;
#pragma unroll
    for (int o2 = 16; o2 > 0; o2 >>= 1) {
        s  += __shfl_xor(s, o2, 64);
        ss += __shfl_xor(ss, o2, 64);
    }
    float mean = s * (1.0f / D);
    float var  = ss * (1.0f / D) - mean * mean;
    float inv  = rsqrtf(var + LN_EPS);

    if (!half) {
        float4 g1 = ((const float4*)gamma)[cl * 2];
        float4 g2 = ((const float4*)gamma)[cl * 2 + 1];
        float4 b1 = ((const float4*)beta)[cl * 2];
        float4 b2 = ((const float4*)beta)[cl * 2 + 1];
        float4 rv1, rv2;
        rv1.x = (acc0.x - mean) * inv * g1.x + b1.x;
        rv1.y = (acc0.y - mean) * inv * g1.y + b1.y;
        rv1.z = (acc1.x - mean) * inv * g1.z + b1.z;
        rv1.w = (acc1.y - mean) * inv * g1.w + b1.w;
        rv2.x = (acc2.x - mean) * inv * g2.x + b2.x;
        rv2.y = (acc2.y - mean) * inv * g2.y + b2.y;
        rv2.z = (acc3.x - mean) * inv * g2.z + b2.z;
        rv2.w = (acc3.y - mean) * inv * g2.w + b2.w;
        float4* o4 = (float4*)out + (size_t)node * 64 + cl * 2;
        o4[0] = rv1;
        o4[1] = rv2;
    }
}

// ---------------------------------------------------------------------------
extern "C" void kernel_launch(void* const* d_in, const int* in_sizes, int n_in,
                              void* d_out, int out_size, void* d_ws, size_t ws_size,
                              hipStream_t stream) {
    const float* feat  = (const float*)d_in[0];
    const float* W0    = (const float*)d_in[1];
    const float* W1    = (const float*)d_in[2];
    const float* W2    = (const float*)d_in[3];
    // d_in[4..6] = a0,a1,a2: unused — attention weights are exactly 1/3
    const float* gamma = (const float*)d_in[7];
    const float* beta  = (const float*)d_in[8];
    const int* src0 = (const int*)d_in[9];
    const int* dst0 = (const int*)d_in[10];
    const int* src1 = (const int*)d_in[11];
    const int* dst1 = (const int*)d_in[12];
    const int* src2 = (const int*)d_in[13];
    const int* dst2 = (const int*)d_in[14];
    float* out = (float*)d_out;

    // workspace layout (R6): h bf16 [N*D] | Wt bf16 [D*D] | deg[150000] |
    // flag[4] | off[150000] | bsum[256] | eidx[1.2M] | rank[1.2M]  (~36.5 MB)
    unsigned short* h  = (unsigned short*)d_ws;
    unsigned short* Wt = h + (size_t)N_NODES * D;
    int* deg  = (int*)(Wt + D * D);
    int* flag = deg + SCAN_N;
    int* off  = flag + 4;
    int* bsum = off + SCAN_N;
    int* eidx = bsum + 256;
    int* rank = eidx + 3 * E_EDGES;

    k_zero_wt<<<ZNB + 256, 256, 0, stream>>>(W0, W1, W2, Wt, (int4*)deg);
    k_main<<<DEG_NB8 + GEMM_NB, 256, 0, stream>>>(dst0, dst1, dst2, deg, rank, flag,
                                                  off, bsum, feat, Wt, h);
    k_fill<<<QNB, 256, 0, stream>>>(src0, dst0, src1, dst1, src2, dst2,
                                    off, bsum, rank, eidx);
    k_gather<<<(N_NODES + 3) / 4, 256, 0, stream>>>(h, eidx, off, bsum, deg,
                                                    gamma, beta, out);
}

// Round 2
// 348.848 us; speedup vs baseline: 1.1888x; 1.1888x over previous
//
#include <hip/hip_runtime.h>

#define N_NODES 50000
#define D       256
#define E_EDGES 400000
#define LN_EPS  1e-5f

#define SCAN_N  (3 * N_NODES)                       // 150000 buckets (r*N+dst)

// ---- two-level counting sort geometry ----
#define NCB     586                                 // coarse bins = ceil(150000/256)
#define EPB     2000                                // edges per hist/scatter block
#define RB_PER  (E_EDGES / EPB)                     // 200 blocks per relation
#define NBA     (3 * RB_PER)                        // 600 hist/scatter blocks
#define GHN     (NCB * NBA)                         // 351600 scan elements
#define GH_NB   ((GHN + 1023) / 1024)               // 344 scan chunks
#define FMAX    12                                  // max 3072 edges per coarse bin
                                                    // (Binomial mean 2048, sigma 45)
#define GB_ROWS 64
#define GEMM_NB ((N_NODES + GB_ROWS - 1) / GB_ROWS) // 782

typedef __attribute__((ext_vector_type(8))) short bf16x8;
typedef __attribute__((ext_vector_type(4))) float f32x4;
typedef __attribute__((ext_vector_type(2))) float f32x2;

__device__ __forceinline__ unsigned short f2bf(float f) {
    unsigned int x = __float_as_uint(f);
    x += 0x7fffu + ((x >> 16) & 1u);     // RNE
    return (unsigned short)(x >> 16);
}

// ---------------------------------------------------------------------------
// K1: blocks [0,256): Wt[n][k] = bf16((W0+W1+W2)[k][n]/3) (MFMA B^T) + flag=0
//     blocks [256,856): coarse histogram — LDS atomics over 586 bins,
//                       write ghist[bin*NBA + blk].  ZERO global atomics.
// (softmax of size-1 tensors == 1; softmax([1,1,1]) == exactly 1/3 each)
// ---------------------------------------------------------------------------
__global__ __launch_bounds__(256) void k_prep2(const float* __restrict__ W0,
                                               const float* __restrict__ W1,
                                               const float* __restrict__ W2,
                                               unsigned short* __restrict__ Wt,
                                               int* __restrict__ flag,
                                               const int* __restrict__ dst0,
                                               const int* __restrict__ dst1,
                                               const int* __restrict__ dst2,
                                               int* __restrict__ ghist) {
    __shared__ int hist[NCB];
    const int b = blockIdx.x, t = threadIdx.x;
    if (b < 256) {
        if (b == 0 && t == 0) flag[0] = 0;
        int i = b * 256 + t;                 // i = n*256 + k
        int n = i >> 8, k = i & 255;
        float v = (W0[k * D + n] + W1[k * D + n] + W2[k * D + n]) * (1.0f / 3.0f);
        Wt[i] = f2bf(v);
        return;
    }
    const int hb = b - 256;                  // 0..599
    for (int i = t; i < NCB; i += 256) hist[i] = 0;
    __syncthreads();
    const int r = hb / RB_PER, rb = hb - r * RB_PER;
    const int4* dq = (const int4*)((r == 0) ? dst0 : (r == 1) ? dst1 : dst2);
    const int qb = rb * (EPB / 4);
    const int rbase = r * N_NODES;
#pragma unroll
    for (int it = 0; it < 2; ++it) {
        int q = t + it * 256;
        if (q < EPB / 4) {
            int4 d = dq[qb + q];
            atomicAdd(&hist[(rbase + d.x) >> 8], 1);
            atomicAdd(&hist[(rbase + d.y) >> 8], 1);
            atomicAdd(&hist[(rbase + d.z) >> 8], 1);
            atomicAdd(&hist[(rbase + d.w) >> 8], 1);
        }
    }
    __syncthreads();
    for (int i = t; i < NCB; i += 256) ghist[i * NBA + hb] = hist[i];
}

// ---------------------------------------------------------------------------
// K2: blocks [0, GH_NB): two-level scan of ghist (in place; chunk-local
//     exclusive values stay in g, chunk bases land in csum via the
//     last-finished block — R6-proven pattern).  Consumers use
//     g[j] + csum[j>>10].
//     blocks [GH_NB, +GEMM_NB): MFMA GEMM h = bf16(feat) @ Wt^T
//     (R1-verified 64-row/256-thread tile) — hides the scan's serial tail.
// ---------------------------------------------------------------------------
__global__ __launch_bounds__(256, 3) void k_scan_gemm(int* __restrict__ g,
                                                      int* __restrict__ csum,
                                                      int* __restrict__ flag,
                                                      const float* __restrict__ feat,
                                                      const unsigned short* __restrict__ Wt,
                                                      unsigned short* __restrict__ h) {
    __shared__ unsigned short sA[GB_ROWS][D + 8];
    __shared__ int wsum[4];
    __shared__ int amLast;
    const int b = blockIdx.x, t = threadIdx.x;
    const int lane = t & 63;

    if (b < GH_NB) {
        const int base = b * 1024 + t * 4;
        int4 v = make_int4(0, 0, 0, 0);
        if (base < GHN) v = *(const int4*)(g + base);   // GHN % 4 == 0
        const int s1 = v.x + v.y, s2 = s1 + v.z, s3 = s2 + v.w;
        int x = s3;
#pragma unroll
        for (int o2 = 1; o2 < 64; o2 <<= 1) {
            int y = __shfl_up(x, o2, 64);
            if (lane >= o2) x += y;
        }
        if (lane == 63) wsum[t >> 6] = x;
        const int texcl = x - s3;
        __syncthreads();
        int wb = 0;
#pragma unroll
        for (int wi = 0; wi < 4; ++wi)
            if (wi < (t >> 6)) wb += wsum[wi];
        const int ex = wb + texcl;
        if (base < GHN) {
            int4 o4 = make_int4(ex, ex + v.x, ex + s1, ex + s2);
            *(int4*)(g + base) = o4;
        }
        if (t == 0) csum[b] = wsum[0] + wsum[1] + wsum[2] + wsum[3];
        __threadfence();
        if (t == 0) amLast = (atomicAdd(flag, 1) == GH_NB - 1);
        __syncthreads();
        if (!amLast) return;
        __threadfence();
        int carry = 0;
        for (int r0 = 0; r0 < GH_NB; r0 += 256) {
            int idx = r0 + t;
            int vv = (idx < GH_NB) ? ((volatile int*)csum)[idx] : 0;
            int x2 = vv;
#pragma unroll
            for (int o2 = 1; o2 < 64; o2 <<= 1) {
                int y = __shfl_up(x2, o2, 64);
                if (lane >= o2) x2 += y;
            }
            if (lane == 63) wsum[t >> 6] = x2;
            __syncthreads();
            int wb2 = 0;
#pragma unroll
            for (int wi = 0; wi < 4; ++wi)
                if (wi < (t >> 6)) wb2 += wsum[wi];
            int tot = wsum[0] + wsum[1] + wsum[2] + wsum[3];
            if (idx < GH_NB) csum[idx] = carry + wb2 + x2 - vv;
            carry += tot;
            __syncthreads();
        }
        return;
    }

    // ---- GEMM path ----
    const int row0 = (b - GH_NB) * GB_ROWS;
    const float4* feat4 = (const float4*)feat;
#pragma unroll
    for (int i = 0; i < 16; ++i) {
        int c = i * 256 + t;
        int r = c >> 6, c4 = c & 63;
        float4 v = make_float4(0.f, 0.f, 0.f, 0.f);
        if (row0 + r < N_NODES) v = feat4[(size_t)(row0 + r) * 64 + c4];
        ushort4 p;
        p.x = f2bf(v.x); p.y = f2bf(v.y); p.z = f2bf(v.z); p.w = f2bf(v.w);
        *(ushort4*)&sA[r][c4 * 4] = p;
    }
    __syncthreads();

    const int w  = t >> 6;
    const int lr = lane & 15;
    const int lq = lane >> 4;

    f32x4 acc[16];
#pragma unroll
    for (int tt = 0; tt < 16; ++tt) acc[tt] = (f32x4){0.f, 0.f, 0.f, 0.f};

    const bf16x8* WtV = (const bf16x8*)Wt;
#pragma unroll
    for (int ks = 0; ks < 8; ++ks) {
        bf16x8 bfr[16];
#pragma unroll
        for (int tt = 0; tt < 16; ++tt)
            bfr[tt] = WtV[(tt * 16 + lr) * 32 + ks * 4 + lq];
        bf16x8 af = *(const bf16x8*)&sA[w * 16 + lr][ks * 32 + lq * 8];
#pragma unroll
        for (int tt = 0; tt < 16; ++tt)
            acc[tt] = __builtin_amdgcn_mfma_f32_16x16x32_bf16(af, bfr[tt], acc[tt], 0, 0, 0);
    }

#pragma unroll
    for (int tt = 0; tt < 16; ++tt) {
#pragma unroll
        for (int j = 0; j < 4; ++j)
            sA[w * 16 + lq * 4 + j][tt * 16 + lr] = f2bf(acc[tt][j]);
    }
    __syncthreads();

#pragma unroll
    for (int i = 0; i < 8; ++i) {
        int c = i * 256 + t;
        int r = c >> 5, cc = c & 31;
        if (row0 + r < N_NODES) {
            uint4 v = *(const uint4*)&sA[r][cc * 8];
            *(uint4*)(h + (size_t)(row0 + r) * D + cc * 8) = v;
        }
    }
}

// ---------------------------------------------------------------------------
// K3: coarse scatter.  Per-block LDS base table sbase[bin] = this block's
// start in bin's segment; LDS atomicAdd returns dense global positions.
// Record = (fine<<16) | src  (src < 50000 fits 16 bits).  ZERO global atomics.
// ---------------------------------------------------------------------------
__global__ __launch_bounds__(256) void k_scatter(const int* __restrict__ src0,
                                                 const int* __restrict__ dst0,
                                                 const int* __restrict__ src1,
                                                 const int* __restrict__ dst1,
                                                 const int* __restrict__ src2,
                                                 const int* __restrict__ dst2,
                                                 const int* __restrict__ g,
                                                 const int* __restrict__ csum,
                                                 unsigned int* __restrict__ coarse) {
    __shared__ int sbase[NCB];
    const int b = blockIdx.x, t = threadIdx.x;
    for (int i = t; i < NCB; i += 256) {
        int j = i * NBA + b;
        sbase[i] = g[j] + csum[j >> 10];
    }
    __syncthreads();
    const int r = b / RB_PER, rb = b - r * RB_PER;
    const int4* sq = (const int4*)((r == 0) ? src0 : (r == 1) ? src1 : src2);
    const int4* dq = (const int4*)((r == 0) ? dst0 : (r == 1) ? dst1 : dst2);
    const int qb = rb * (EPB / 4);
    const int rbase = r * N_NODES;
#pragma unroll
    for (int it = 0; it < 2; ++it) {
        int q = t + it * 256;
        if (q < EPB / 4) {
            int4 s = sq[qb + q];
            int4 d = dq[qb + q];
            int bk, p;
            bk = rbase + d.x; p = atomicAdd(&sbase[bk >> 8], 1);
            coarse[p] = ((unsigned)(bk & 255) << 16) | (unsigned)s.x;
            bk = rbase + d.y; p = atomicAdd(&sbase[bk >> 8], 1);
            coarse[p] = ((unsigned)(bk & 255) << 16) | (unsigned)s.y;
            bk = rbase + d.z; p = atomicAdd(&sbase[bk >> 8], 1);
            coarse[p] = ((unsigned)(bk & 255) << 16) | (unsigned)s.z;
            bk = rbase + d.w; p = atomicAdd(&sbase[bk >> 8], 1);
            coarse[p] = ((unsigned)(bk & 255) << 16) | (unsigned)s.w;
        }
    }
}

// ---------------------------------------------------------------------------
// K4: fine CSR.  One block per coarse bin (contiguous ~2048 records):
// LDS 256-bin histogram (atomic returns = local rank) + block scan ->
// final eidx (ushort src), deg[bucket], off[bucket].  ZERO global atomics.
// ---------------------------------------------------------------------------
__global__ __launch_bounds__(256) void k_fine(const unsigned int* __restrict__ coarse,
                                              const int* __restrict__ g,
                                              const int* __restrict__ csum,
                                              int* __restrict__ deg,
                                              int* __restrict__ off,
                                              unsigned short* __restrict__ eidx) {
    __shared__ int fh[256], fb[256], wsum[4];
    const int c = blockIdx.x, t = threadIdx.x, lane = t & 63;
    const int j0 = c * NBA;
    const int S = g[j0] + csum[j0 >> 10];
    const int E = (c + 1 < NCB) ? (g[j0 + NBA] + csum[(j0 + NBA) >> 10]) : (3 * E_EDGES);
    const int cnt = E - S;
    fh[t] = 0;
    __syncthreads();
    unsigned int recs[FMAX];
    int lrk[FMAX];
#pragma unroll
    for (int it = 0; it < FMAX; ++it) {
        int i = t + it * 256;
        recs[it] = 0; lrk[it] = 0;
        if (i < cnt) {
            unsigned int rec = coarse[S + i];
            recs[it] = rec;
            lrk[it] = atomicAdd(&fh[rec >> 16], 1);
        }
    }
    __syncthreads();
    const int v = fh[t];
    int x = v;
#pragma unroll
    for (int o2 = 1; o2 < 64; o2 <<= 1) {
        int y = __shfl_up(x, o2, 64);
        if (lane >= o2) x += y;
    }
    if (lane == 63) wsum[t >> 6] = x;
    __syncthreads();
    int wb = 0;
#pragma unroll
    for (int wi = 0; wi < 4; ++wi)
        if (wi < (t >> 6)) wb += wsum[wi];
    const int ex = wb + x - v;
    fb[t] = ex;
    const int bucket = c * 256 + t;
    if (bucket < SCAN_N) {
        deg[bucket] = v;
        off[bucket] = S + ex;
    }
    __syncthreads();
#pragma unroll
    for (int it = 0; it < FMAX; ++it) {
        int i = t + it * 256;
        if (i < cnt) {
            unsigned int rec = recs[it];
            eidx[S + fb[rec >> 16] + lrk[it]] = (unsigned short)(rec & 0xffffu);
        }
    }
}

// ---------------------------------------------------------------------------
// K5: fused gather + ReLU + LayerNorm (R1-verified structure, bsum removed).
// One node per wave; half-waves own even/odd edges; 16B uint4 row loads;
// wave-uniform eidx reads.
// ---------------------------------------------------------------------------
__device__ __forceinline__ void pair_acc(const uint4* __restrict__ h4, int sa, int sb,
                                         int half, int cl,
                                         f32x2& a0, f32x2& a1, f32x2& a2, f32x2& a3) {
    int su = half ? sb : sa;
    uint4 u = h4[(size_t)su * 32 + cl];
    f32x2 v;
    v.x = __uint_as_float(u.x << 16); v.y = __uint_as_float(u.x & 0xffff0000u); a0 += v;
    v.x = __uint_as_float(u.y << 16); v.y = __uint_as_float(u.y & 0xffff0000u); a1 += v;
    v.x = __uint_as_float(u.z << 16); v.y = __uint_as_float(u.z & 0xffff0000u); a2 += v;
    v.x = __uint_as_float(u.w << 16); v.y = __uint_as_float(u.w & 0xffff0000u); a3 += v;
}

__global__ __launch_bounds__(256) void k_gather(const unsigned short* __restrict__ h,
                                                const unsigned short* __restrict__ eidx,
                                                const int* __restrict__ off,
                                                const int* __restrict__ deg,
                                                const float* __restrict__ gamma,
                                                const float* __restrict__ beta,
                                                float* __restrict__ out) {
    int node = blockIdx.x * 4 + (threadIdx.x >> 6);
    if (node >= N_NODES) return;
    const int lane = threadIdx.x & 63;
    const int half = lane >> 5;          // 0: even edges, 1: odd edges
    const int cl   = lane & 31;          // channel block: ch [cl*8, cl*8+8)
    const uint4* h4 = (const uint4*)h;

    f32x2 acc0 = (f32x2)0.f, acc1 = (f32x2)0.f, acc2 = (f32x2)0.f, acc3 = (f32x2)0.f;
#pragma unroll
    for (int r = 0; r < 3; ++r) {
        int idx = r * N_NODES + node;
        int dg = deg[idx];
        int start = off[idx];
        int end = start + dg;
        float wgt = 1.0f / (3.0f * (float)(dg > 1 ? dg : 1));
        f32x2 r0 = (f32x2)0.f, r1 = (f32x2)0.f, r2 = (f32x2)0.f, r3 = (f32x2)0.f;

        int k = start;
        for (; k + 8 <= end; k += 8) {           // 8 edges = 4 pair-loads
            int kk = __builtin_amdgcn_readfirstlane(k);
            int s0 = eidx[kk + 0], s1 = eidx[kk + 1], s2 = eidx[kk + 2], s3 = eidx[kk + 3];
            int s4 = eidx[kk + 4], s5 = eidx[kk + 5], s6 = eidx[kk + 6], s7 = eidx[kk + 7];
            pair_acc(h4, s0, s1, half, cl, r0, r1, r2, r3);
            pair_acc(h4, s2, s3, half, cl, r0, r1, r2, r3);
            pair_acc(h4, s4, s5, half, cl, r0, r1, r2, r3);
            pair_acc(h4, s6, s7, half, cl, r0, r1, r2, r3);
        }
        if (k + 4 <= end) {                      // 4 edges = 2 pair-loads
            int kk = __builtin_amdgcn_readfirstlane(k);
            int s0 = eidx[kk + 0], s1 = eidx[kk + 1], s2 = eidx[kk + 2], s3 = eidx[kk + 3];
            pair_acc(h4, s0, s1, half, cl, r0, r1, r2, r3);
            pair_acc(h4, s2, s3, half, cl, r0, r1, r2, r3);
            k += 4;
        }
        if (k + 2 <= end) {                      // 2 edges = 1 pair-load
            int kk = __builtin_amdgcn_readfirstlane(k);
            int s0 = eidx[kk + 0], s1 = eidx[kk + 1];
            pair_acc(h4, s0, s1, half, cl, r0, r1, r2, r3);
            k += 2;
        }
        if (k < end) {                           // tail edge: lower half only
            int s0 = eidx[__builtin_amdgcn_readfirstlane(k)];
            if (!half) {
                uint4 u = h4[(size_t)s0 * 32 + cl];
                f32x2 v;
                v.x = __uint_as_float(u.x << 16); v.y = __uint_as_float(u.x & 0xffff0000u); r0 += v;
                v.x = __uint_as_float(u.y << 16); v.y = __uint_as_float(u.y & 0xffff0000u); r1 += v;
                v.x = __uint_as_float(u.z << 16); v.y = __uint_as_float(u.z & 0xffff0000u); r2 += v;
                v.x = __uint_as_float(u.w << 16); v.y = __uint_as_float(u.w & 0xffff0000u); r3 += v;
            }
        }
        acc0 += r0 * wgt;
        acc1 += r1 * wgt;
        acc2 += r2 * wgt;
        acc3 += r3 * wgt;
    }

    // combine even/odd halves (both halves end up with the full sums)
    acc0.x += __shfl_xor(acc0.x, 32, 64); acc0.y += __shfl_xor(acc0.y, 32, 64);
    acc1.x += __shfl_xor(acc1.x, 32, 64); acc1.y += __shfl_xor(acc1.y, 32, 64);
    acc2.x += __shfl_xor(acc2.x, 32, 64); acc2.y += __shfl_xor(acc2.y, 32, 64);
    acc3.x += __shfl_xor(acc3.x, 32, 64); acc3.y += __shfl_xor(acc3.y, 32, 64);

    // ReLU
    acc0.x = fmaxf(acc0.x, 0.f); acc0.y = fmaxf(acc0.y, 0.f);
    acc1.x = fmaxf(acc1.x, 0.f); acc1.y = fmaxf(acc1.y, 0.f);
    acc2.x = fmaxf(acc2.x, 0.f); acc2.y = fmaxf(acc2.y, 0.f);
    acc3.x = fmaxf(acc3.x, 0.f); acc3.y = fmaxf(acc3.y, 0.f);

    // LayerNorm: each 32-lane half holds identical data; reduce within half
    float s  = acc0.x + acc0.y + acc1.x + acc1.y + acc2.x + acc2.y + acc3.x + acc3.y;
    float ss = acc0.x * acc0.x + acc0.y * acc0.y + acc1.x * acc1.x + acc1.y * acc1.y
             + acc2.x * acc2.x + acc2.y * acc2.y + acc3.x * acc3.x + acc3.y * acc3.y;
#pragma unroll
    for (int o2 = 16; o2 > 0; o2 >>= 1) {
        s  += __shfl_xor(s, o2, 64);
        ss += __shfl_xor(ss, o2, 64);
    }
    float mean = s * (1.0f / D);
    float var  = ss * (1.0f / D) - mean * mean;
    float inv  = rsqrtf(var + LN_EPS);

    if (!half) {
        float4 g1 = ((const float4*)gamma)[cl * 2];
        float4 g2 = ((const float4*)gamma)[cl * 2 + 1];
        float4 b1 = ((const float4*)beta)[cl * 2];
        float4 b2 = ((const float4*)beta)[cl * 2 + 1];
        float4 rv1, rv2;
        rv1.x = (acc0.x - mean) * inv * g1.x + b1.x;
        rv1.y = (acc0.y - mean) * inv * g1.y + b1.y;
        rv1.z = (acc1.x - mean) * inv * g1.z + b1.z;
        rv1.w = (acc1.y - mean) * inv * g1.w + b1.w;
        rv2.x = (acc2.x - mean) * inv * g2.x + b2.x;
        rv2.y = (acc2.y - mean) * inv * g2.y + b2.y;
        rv2.z = (acc3.x - mean) * inv * g2.z + b2.z;
        rv2.w = (acc3.y - mean) * inv * g2.w + b2.w;
        float4* o4 = (float4*)out + (size_t)node * 64 + cl * 2;
        o4[0] = rv1;
        o4[1] = rv2;
    }
}

// ---------------------------------------------------------------------------
extern "C" void kernel_launch(void* const* d_in, const int* in_sizes, int n_in,
                              void* d_out, int out_size, void* d_ws, size_t ws_size,
                              hipStream_t stream) {
    const float* feat  = (const float*)d_in[0];
    const float* W0    = (const float*)d_in[1];
    const float* W1    = (const float*)d_in[2];
    const float* W2    = (const float*)d_in[3];
    // d_in[4..6] = a0,a1,a2: unused — attention weights are exactly 1/3
    const float* gamma = (const float*)d_in[7];
    const float* beta  = (const float*)d_in[8];
    const int* src0 = (const int*)d_in[9];
    const int* dst0 = (const int*)d_in[10];
    const int* src1 = (const int*)d_in[11];
    const int* dst1 = (const int*)d_in[12];
    const int* src2 = (const int*)d_in[13];
    const int* dst2 = (const int*)d_in[14];
    float* out = (float*)d_out;

    // workspace: h bf16[N*D] | Wt bf16[D*D] | deg[150000] | off[150000] |
    // flag[4] | csum[352] | ghist[351600] | coarse u32[1.2M] | eidx u16[1.2M]
    // total ~35.7 MB
    unsigned short* h  = (unsigned short*)d_ws;
    unsigned short* Wt = h + (size_t)N_NODES * D;
    int* deg    = (int*)(Wt + D * D);
    int* off    = deg + SCAN_N;
    int* flag   = off + SCAN_N;
    int* csum   = flag + 4;
    int* ghist  = csum + 352;
    unsigned int*   coarse = (unsigned int*)(ghist + GHN);
    unsigned short* eidx   = (unsigned short*)(coarse + 3 * E_EDGES);

    k_prep2<<<256 + NBA, 256, 0, stream>>>(W0, W1, W2, Wt, flag,
                                           dst0, dst1, dst2, ghist);
    k_scan_gemm<<<GH_NB + GEMM_NB, 256, 0, stream>>>(ghist, csum, flag, feat, Wt, h);
    k_scatter<<<NBA, 256, 0, stream>>>(src0, dst0, src1, dst1, src2, dst2,
                                       ghist, csum, coarse);
    k_fine<<<NCB, 256, 0, stream>>>(coarse, ghist, csum, deg, off, eidx);
    k_gather<<<(N_NODES + 3) / 4, 256, 0, stream>>>(h, eidx, off, deg,
                                                    gamma, beta, out);
}

// Round 3
// 300.851 us; speedup vs baseline: 1.3784x; 1.1595x over previous
//
#include <hip/hip_runtime.h>

#define N_NODES 50000
#define D       256
#define E_EDGES 400000
#define LN_EPS  1e-5f

#define SCAN_N  (3 * N_NODES)                       // 150000 buckets (r*N+dst)

// ---- two-level counting sort geometry ----
#define NCB     586                                 // coarse bins = ceil(150000/256)
#define EPB     2000                                // edges per hist/scatter block
#define RB_PER  (E_EDGES / EPB)                     // 200 blocks per relation
#define NBA     (3 * RB_PER)                        // 600 hist/scatter blocks
#define GHN     (NCB * NBA)                         // 351600 scan elements
#define GH_NB   ((GHN + 1023) / 1024)               // 344 scan chunks
#define FMAX    12                                  // max 3072 edges per coarse bin
                                                    // (Binomial mean 2048, sigma 45)
#define GB_ROWS 64
#define GEMM_NB ((N_NODES + GB_ROWS - 1) / GB_ROWS) // 782

typedef __attribute__((ext_vector_type(8))) short bf16x8;
typedef __attribute__((ext_vector_type(4))) float f32x4;
typedef __attribute__((ext_vector_type(2))) float f32x2;

__device__ __forceinline__ unsigned short f2bf(float f) {
    unsigned int x = __float_as_uint(f);
    x += 0x7fffu + ((x >> 16) & 1u);     // RNE
    return (unsigned short)(x >> 16);
}
__device__ __forceinline__ unsigned int pack2(float lo, float hi) {
    return (unsigned int)f2bf(lo) | ((unsigned int)f2bf(hi) << 16);
}

// ---------------------------------------------------------------------------
// K1: blocks [0,256): Wt[n][k] = bf16((W0+W1+W2)[k][n]/3) (MFMA B^T) + flag=0
//     blocks [256,856): coarse histogram — LDS atomics over 586 bins,
//                       write ghist[bin*NBA + blk].  ZERO global atomics.
// (softmax of size-1 tensors == 1; softmax([1,1,1]) == exactly 1/3 each)
// ---------------------------------------------------------------------------
__global__ __launch_bounds__(256) void k_prep2(const float* __restrict__ W0,
                                               const float* __restrict__ W1,
                                               const float* __restrict__ W2,
                                               unsigned short* __restrict__ Wt,
                                               int* __restrict__ flag,
                                               const int* __restrict__ dst0,
                                               const int* __restrict__ dst1,
                                               const int* __restrict__ dst2,
                                               int* __restrict__ ghist) {
    __shared__ int hist[NCB];
    const int b = blockIdx.x, t = threadIdx.x;
    if (b < 256) {
        if (b == 0 && t == 0) flag[0] = 0;
        int i = b * 256 + t;                 // i = n*256 + k
        int n = i >> 8, k = i & 255;
        float v = (W0[k * D + n] + W1[k * D + n] + W2[k * D + n]) * (1.0f / 3.0f);
        Wt[i] = f2bf(v);
        return;
    }
    const int hb = b - 256;                  // 0..599
    for (int i = t; i < NCB; i += 256) hist[i] = 0;
    __syncthreads();
    const int r = hb / RB_PER, rb = hb - r * RB_PER;
    const int4* dq = (const int4*)((r == 0) ? dst0 : (r == 1) ? dst1 : dst2);
    const int qb = rb * (EPB / 4);
    const int rbase = r * N_NODES;
#pragma unroll
    for (int it = 0; it < 2; ++it) {
        int q = t + it * 256;
        if (q < EPB / 4) {
            int4 d = dq[qb + q];
            atomicAdd(&hist[(rbase + d.x) >> 8], 1);
            atomicAdd(&hist[(rbase + d.y) >> 8], 1);
            atomicAdd(&hist[(rbase + d.z) >> 8], 1);
            atomicAdd(&hist[(rbase + d.w) >> 8], 1);
        }
    }
    __syncthreads();
    for (int i = t; i < NCB; i += 256) ghist[i * NBA + hb] = hist[i];
}

// ---------------------------------------------------------------------------
// K2: blocks [0, GH_NB): two-level scan of ghist (R6-proven pattern).
//     blocks [GH_NB, +GEMM_NB): MFMA GEMM h = bf16(feat) @ Wt^T with
//     LDS-STAGED B (this round's change): K-tiled BK=64, Wt slice staged
//     coalesced once per block into padded LDS (+8 elem pad -> balanced
//     8-lanes-per-bank-group ds_read_b128), A slice staged+converted per
//     K-step.  Replaces per-wave scattered global Wt reads (was ~110us).
// ---------------------------------------------------------------------------
__global__ __launch_bounds__(256, 3) void k_scan_gemm(int* __restrict__ g,
                                                      int* __restrict__ csum,
                                                      int* __restrict__ flag,
                                                      const float* __restrict__ feat,
                                                      const unsigned short* __restrict__ Wt,
                                                      unsigned short* __restrict__ h) {
    __shared__ unsigned short sB[256][72];   // 36864 B: Wt[0:256][k0:k0+64)
    __shared__ unsigned short sAk[64][72];   //  9216 B: bf16 A slice
    __shared__ int wsum[4];
    __shared__ int amLast;
    const int b = blockIdx.x, t = threadIdx.x;
    const int lane = t & 63;

    if (b < GH_NB) {
        const int base = b * 1024 + t * 4;
        int4 v = make_int4(0, 0, 0, 0);
        if (base < GHN) v = *(const int4*)(g + base);   // GHN % 4 == 0
        const int s1 = v.x + v.y, s2 = s1 + v.z, s3 = s2 + v.w;
        int x = s3;
#pragma unroll
        for (int o2 = 1; o2 < 64; o2 <<= 1) {
            int y = __shfl_up(x, o2, 64);
            if (lane >= o2) x += y;
        }
        if (lane == 63) wsum[t >> 6] = x;
        const int texcl = x - s3;
        __syncthreads();
        int wb = 0;
#pragma unroll
        for (int wi = 0; wi < 4; ++wi)
            if (wi < (t >> 6)) wb += wsum[wi];
        const int ex = wb + texcl;
        if (base < GHN) {
            int4 o4 = make_int4(ex, ex + v.x, ex + s1, ex + s2);
            *(int4*)(g + base) = o4;
        }
        if (t == 0) csum[b] = wsum[0] + wsum[1] + wsum[2] + wsum[3];
        __threadfence();
        if (t == 0) amLast = (atomicAdd(flag, 1) == GH_NB - 1);
        __syncthreads();
        if (!amLast) return;
        __threadfence();
        int carry = 0;
        for (int r0 = 0; r0 < GH_NB; r0 += 256) {
            int idx = r0 + t;
            int vv = (idx < GH_NB) ? ((volatile int*)csum)[idx] : 0;
            int x2 = vv;
#pragma unroll
            for (int o2 = 1; o2 < 64; o2 <<= 1) {
                int y = __shfl_up(x2, o2, 64);
                if (lane >= o2) x2 += y;
            }
            if (lane == 63) wsum[t >> 6] = x2;
            __syncthreads();
            int wb2 = 0;
#pragma unroll
            for (int wi = 0; wi < 4; ++wi)
                if (wi < (t >> 6)) wb2 += wsum[wi];
            int tot = wsum[0] + wsum[1] + wsum[2] + wsum[3];
            if (idx < GH_NB) csum[idx] = carry + wb2 + x2 - vv;
            carry += tot;
            __syncthreads();
        }
        return;
    }

    // ---- GEMM path: K-tiled, LDS-staged B ----
    const int row0 = (b - GH_NB) * GB_ROWS;
    const float4* feat4 = (const float4*)feat;
    const int w  = t >> 6;
    const int lr = lane & 15;
    const int lq = lane >> 4;
    const int ar  = t >> 2, aseg = t & 3;    // A staging: 64 rows x 4 segs

    f32x4 acc[16];
#pragma unroll
    for (int tt = 0; tt < 16; ++tt) acc[tt] = (f32x4){0.f, 0.f, 0.f, 0.f};

#pragma unroll
    for (int ks2 = 0; ks2 < 4; ++ks2) {
        if (ks2) __syncthreads();            // protect prev-tile reads
        // stage B: Wt[n][ks2*64 .. +64), 8x 16B chunks per thread, coalesced
#pragma unroll
        for (int i = 0; i < 8; ++i) {
            int chunk = i * 256 + t;         // 0..2047
            int n = chunk >> 3, c = chunk & 7;
            uint4 v = *(const uint4*)(Wt + n * 256 + ks2 * 64 + c * 8);
            *(uint4*)&sB[n][c * 8] = v;
        }
        // stage A: feat[row0+ar][ks2*64 + aseg*16 .. +16) -> bf16
        {
            float4 a0 = make_float4(0.f, 0.f, 0.f, 0.f), a1 = a0, a2 = a0, a3 = a0;
            if (row0 + ar < N_NODES) {
                const float4* fp = feat4 + (size_t)(row0 + ar) * 64 + ks2 * 16 + aseg * 4;
                a0 = fp[0]; a1 = fp[1]; a2 = fp[2]; a3 = fp[3];
            }
            uint4 p0, p1;
            p0.x = pack2(a0.x, a0.y); p0.y = pack2(a0.z, a0.w);
            p0.z = pack2(a1.x, a1.y); p0.w = pack2(a1.z, a1.w);
            p1.x = pack2(a2.x, a2.y); p1.y = pack2(a2.z, a2.w);
            p1.z = pack2(a3.x, a3.y); p1.w = pack2(a3.z, a3.w);
            *(uint4*)&sAk[ar][aseg * 16]     = p0;
            *(uint4*)&sAk[ar][aseg * 16 + 8] = p1;
        }
        __syncthreads();
        // compute: 2 k-slices of 32
#pragma unroll
        for (int kk = 0; kk < 2; ++kk) {
            bf16x8 af = *(const bf16x8*)&sAk[w * 16 + lr][kk * 32 + lq * 8];
            bf16x8 bfr[16];
#pragma unroll
            for (int tt = 0; tt < 16; ++tt)
                bfr[tt] = *(const bf16x8*)&sB[tt * 16 + lr][kk * 32 + lq * 8];
#pragma unroll
            for (int tt = 0; tt < 16; ++tt)
                acc[tt] = __builtin_amdgcn_mfma_f32_16x16x32_bf16(af, bfr[tt], acc[tt], 0, 0, 0);
        }
    }

    // epilogue: acc -> bf16 via LDS (reuse sB as [64][264]), then store
    __syncthreads();
    unsigned short* sC = &sB[0][0];          // 64 x 264 = 33792 ushorts <= sB
#pragma unroll
    for (int tt = 0; tt < 16; ++tt) {
#pragma unroll
        for (int j = 0; j < 4; ++j)
            sC[(w * 16 + lq * 4 + j) * 264 + tt * 16 + lr] = f2bf(acc[tt][j]);
    }
    __syncthreads();

#pragma unroll
    for (int i = 0; i < 8; ++i) {
        int c = i * 256 + t;
        int r = c >> 5, cc = c & 31;
        if (row0 + r < N_NODES) {
            uint4 v = *(const uint4*)&sC[r * 264 + cc * 8];
            *(uint4*)(h + (size_t)(row0 + r) * D + cc * 8) = v;
        }
    }
}

// ---------------------------------------------------------------------------
// K3: coarse scatter.  Per-block LDS base table sbase[bin] = this block's
// start in bin's segment; LDS atomicAdd returns dense global positions.
// Record = (fine<<16) | src  (src < 50000 fits 16 bits).  ZERO global atomics.
// ---------------------------------------------------------------------------
__global__ __launch_bounds__(256) void k_scatter(const int* __restrict__ src0,
                                                 const int* __restrict__ dst0,
                                                 const int* __restrict__ src1,
                                                 const int* __restrict__ dst1,
                                                 const int* __restrict__ src2,
                                                 const int* __restrict__ dst2,
                                                 const int* __restrict__ g,
                                                 const int* __restrict__ csum,
                                                 unsigned int* __restrict__ coarse) {
    __shared__ int sbase[NCB];
    const int b = blockIdx.x, t = threadIdx.x;
    for (int i = t; i < NCB; i += 256) {
        int j = i * NBA + b;
        sbase[i] = g[j] + csum[j >> 10];
    }
    __syncthreads();
    const int r = b / RB_PER, rb = b - r * RB_PER;
    const int4* sq = (const int4*)((r == 0) ? src0 : (r == 1) ? src1 : src2);
    const int4* dq = (const int4*)((r == 0) ? dst0 : (r == 1) ? dst1 : dst2);
    const int qb = rb * (EPB / 4);
    const int rbase = r * N_NODES;
#pragma unroll
    for (int it = 0; it < 2; ++it) {
        int q = t + it * 256;
        if (q < EPB / 4) {
            int4 s = sq[qb + q];
            int4 d = dq[qb + q];
            int bk, p;
            bk = rbase + d.x; p = atomicAdd(&sbase[bk >> 8], 1);
            coarse[p] = ((unsigned)(bk & 255) << 16) | (unsigned)s.x;
            bk = rbase + d.y; p = atomicAdd(&sbase[bk >> 8], 1);
            coarse[p] = ((unsigned)(bk & 255) << 16) | (unsigned)s.y;
            bk = rbase + d.z; p = atomicAdd(&sbase[bk >> 8], 1);
            coarse[p] = ((unsigned)(bk & 255) << 16) | (unsigned)s.z;
            bk = rbase + d.w; p = atomicAdd(&sbase[bk >> 8], 1);
            coarse[p] = ((unsigned)(bk & 255) << 16) | (unsigned)s.w;
        }
    }
}

// ---------------------------------------------------------------------------
// K4: fine CSR.  One block per coarse bin (contiguous ~2048 records):
// LDS 256-bin histogram (atomic returns = local rank) + block scan ->
// final eidx (ushort src), deg[bucket], off[bucket].  ZERO global atomics.
// ---------------------------------------------------------------------------
__global__ __launch_bounds__(256) void k_fine(const unsigned int* __restrict__ coarse,
                                              const int* __restrict__ g,
                                              const int* __restrict__ csum,
                                              int* __restrict__ deg,
                                              int* __restrict__ off,
                                              unsigned short* __restrict__ eidx) {
    __shared__ int fh[256], fb[256], wsum[4];
    const int c = blockIdx.x, t = threadIdx.x, lane = t & 63;
    const int j0 = c * NBA;
    const int S = g[j0] + csum[j0 >> 10];
    const int E = (c + 1 < NCB) ? (g[j0 + NBA] + csum[(j0 + NBA) >> 10]) : (3 * E_EDGES);
    const int cnt = E - S;
    fh[t] = 0;
    __syncthreads();
    unsigned int recs[FMAX];
    int lrk[FMAX];
#pragma unroll
    for (int it = 0; it < FMAX; ++it) {
        int i = t + it * 256;
        recs[it] = 0; lrk[it] = 0;
        if (i < cnt) {
            unsigned int rec = coarse[S + i];
            recs[it] = rec;
            lrk[it] = atomicAdd(&fh[rec >> 16], 1);
        }
    }
    __syncthreads();
    const int v = fh[t];
    int x = v;
#pragma unroll
    for (int o2 = 1; o2 < 64; o2 <<= 1) {
        int y = __shfl_up(x, o2, 64);
        if (lane >= o2) x += y;
    }
    if (lane == 63) wsum[t >> 6] = x;
    __syncthreads();
    int wb = 0;
#pragma unroll
    for (int wi = 0; wi < 4; ++wi)
        if (wi < (t >> 6)) wb += wsum[wi];
    const int ex = wb + x - v;
    fb[t] = ex;
    const int bucket = c * 256 + t;
    if (bucket < SCAN_N) {
        deg[bucket] = v;
        off[bucket] = S + ex;
    }
    __syncthreads();
#pragma unroll
    for (int it = 0; it < FMAX; ++it) {
        int i = t + it * 256;
        if (i < cnt) {
            unsigned int rec = recs[it];
            eidx[S + fb[rec >> 16] + lrk[it]] = (unsigned short)(rec & 0xffffu);
        }
    }
}

// ---------------------------------------------------------------------------
// K5: fused gather + ReLU + LayerNorm (R1-verified structure).
// One node per wave; half-waves own even/odd edges; 16B uint4 row loads;
// wave-uniform eidx reads.
// ---------------------------------------------------------------------------
__device__ __forceinline__ void pair_acc(const uint4* __restrict__ h4, int sa, int sb,
                                         int half, int cl,
                                         f32x2& a0, f32x2& a1, f32x2& a2, f32x2& a3) {
    int su = half ? sb : sa;
    uint4 u = h4[(size_t)su * 32 + cl];
    f32x2 v;
    v.x = __uint_as_float(u.x << 16); v.y = __uint_as_float(u.x & 0xffff0000u); a0 += v;
    v.x = __uint_as_float(u.y << 16); v.y = __uint_as_float(u.y & 0xffff0000u); a1 += v;
    v.x = __uint_as_float(u.z << 16); v.y = __uint_as_float(u.z & 0xffff0000u); a2 += v;
    v.x = __uint_as_float(u.w << 16); v.y = __uint_as_float(u.w & 0xffff0000u); a3 += v;
}

__global__ __launch_bounds__(256) void k_gather(const unsigned short* __restrict__ h,
                                                const unsigned short* __restrict__ eidx,
                                                const int* __restrict__ off,
                                                const int* __restrict__ deg,
                                                const float* __restrict__ gamma,
                                                const float* __restrict__ beta,
                                                float* __restrict__ out) {
    int node = blockIdx.x * 4 + (threadIdx.x >> 6);
    if (node >= N_NODES) return;
    const int lane = threadIdx.x & 63;
    const int half = lane >> 5;          // 0: even edges, 1: odd edges
    const int cl   = lane & 31;          // channel block: ch [cl*8, cl*8+8)
    const uint4* h4 = (const uint4*)h;

    f32x2 acc0 = (f32x2)0.f, acc1 = (f32x2)0.f, acc2 = (f32x2)0.f, acc3 = (f32x2)0.f;
#pragma unroll
    for (int r = 0; r < 3; ++r) {
        int idx = r * N_NODES + node;
        int dg = deg[idx];
        int start = off[idx];
        int end = start + dg;
        float wgt = 1.0f / (3.0f * (float)(dg > 1 ? dg : 1));
        f32x2 r0 = (f32x2)0.f, r1 = (f32x2)0.f, r2 = (f32x2)0.f, r3 = (f32x2)0.f;

        int k = start;
        for (; k + 8 <= end; k += 8) {           // 8 edges = 4 pair-loads
            int kk = __builtin_amdgcn_readfirstlane(k);
            int s0 = eidx[kk + 0], s1 = eidx[kk + 1], s2 = eidx[kk + 2], s3 = eidx[kk + 3];
            int s4 = eidx[kk + 4], s5 = eidx[kk + 5], s6 = eidx[kk + 6], s7 = eidx[kk + 7];
            pair_acc(h4, s0, s1, half, cl, r0, r1, r2, r3);
            pair_acc(h4, s2, s3, half, cl, r0, r1, r2, r3);
            pair_acc(h4, s4, s5, half, cl, r0, r1, r2, r3);
            pair_acc(h4, s6, s7, half, cl, r0, r1, r2, r3);
        }
        if (k + 4 <= end) {                      // 4 edges = 2 pair-loads
            int kk = __builtin_amdgcn_readfirstlane(k);
            int s0 = eidx[kk + 0], s1 = eidx[kk + 1], s2 = eidx[kk + 2], s3 = eidx[kk + 3];
            pair_acc(h4, s0, s1, half, cl, r0, r1, r2, r3);
            pair_acc(h4, s2, s3, half, cl, r0, r1, r2, r3);
            k += 4;
        }
        if (k + 2 <= end) {                      // 2 edges = 1 pair-load
            int kk = __builtin_amdgcn_readfirstlane(k);
            int s0 = eidx[kk + 0], s1 = eidx[kk + 1];
            pair_acc(h4, s0, s1, half, cl, r0, r1, r2, r3);
            k += 2;
        }
        if (k < end) {                           // tail edge: lower half only
            int s0 = eidx[__builtin_amdgcn_readfirstlane(k)];
            if (!half) {
                uint4 u = h4[(size_t)s0 * 32 + cl];
                f32x2 v;
                v.x = __uint_as_float(u.x << 16); v.y = __uint_as_float(u.x & 0xffff0000u); r0 += v;
                v.x = __uint_as_float(u.y << 16); v.y = __uint_as_float(u.y & 0xffff0000u); r1 += v;
                v.x = __uint_as_float(u.z << 16); v.y = __uint_as_float(u.z & 0xffff0000u); r2 += v;
                v.x = __uint_as_float(u.w << 16); v.y = __uint_as_float(u.w & 0xffff0000u); r3 += v;
            }
        }
        acc0 += r0 * wgt;
        acc1 += r1 * wgt;
        acc2 += r2 * wgt;
        acc3 += r3 * wgt;
    }

    // combine even/odd halves (both halves end up with the full sums)
    acc0.x += __shfl_xor(acc0.x, 32, 64); acc0.y += __shfl_xor(acc0.y, 32, 64);
    acc1.x += __shfl_xor(acc1.x, 32, 64); acc1.y += __shfl_xor(acc1.y, 32, 64);
    acc2.x += __shfl_xor(acc2.x, 32, 64); acc2.y += __shfl_xor(acc2.y, 32, 64);
    acc3.x += __shfl_xor(acc3.x, 32, 64); acc3.y += __shfl_xor(acc3.y, 32, 64);

    // ReLU
    acc0.x = fmaxf(acc0.x, 0.f); acc0.y = fmaxf(acc0.y, 0.f);
    acc1.x = fmaxf(acc1.x, 0.f); acc1.y = fmaxf(acc1.y, 0.f);
    acc2.x = fmaxf(acc2.x, 0.f); acc2.y = fmaxf(acc2.y, 0.f);
    acc3.x = fmaxf(acc3.x, 0.f); acc3.y = fmaxf(acc3.y, 0.f);

    // LayerNorm: each 32-lane half holds identical data; reduce within half
    float s  = acc0.x + acc0.y + acc1.x + acc1.y + acc2.x + acc2.y + acc3.x + acc3.y;
    float ss = acc0.x * acc0.x + acc0.y * acc0.y + acc1.x * acc1.x + acc1.y * acc1.y
             + acc2.x * acc2.x + acc2.y * acc2.y + acc3.x * acc3.x + acc3.y * acc3.y;
#pragma unroll
    for (int o2 = 16; o2 > 0; o2 >>= 1) {
        s  += __shfl_xor(s, o2, 64);
        ss += __shfl_xor(ss, o2, 64);
    }
    float mean = s * (1.0f / D);
    float var  = ss * (1.0f / D) - mean * mean;
    float inv  = rsqrtf(var + LN_EPS);

    if (!half) {
        float4 g1 = ((const float4*)gamma)[cl * 2];
        float4 g2 = ((const float4*)gamma)[cl * 2 + 1];
        float4 b1 = ((const float4*)beta)[cl * 2];
        float4 b2 = ((const float4*)beta)[cl * 2 + 1];
        float4 rv1, rv2;
        rv1.x = (acc0.x - mean) * inv * g1.x + b1.x;
        rv1.y = (acc0.y - mean) * inv * g1.y + b1.y;
        rv1.z = (acc1.x - mean) * inv * g1.z + b1.z;
        rv1.w = (acc1.y - mean) * inv * g1.w + b1.w;
        rv2.x = (acc2.x - mean) * inv * g2.x + b2.x;
        rv2.y = (acc2.y - mean) * inv * g2.y + b2.y;
        rv2.z = (acc3.x - mean) * inv * g2.z + b2.z;
        rv2.w = (acc3.y - mean) * inv * g2.w + b2.w;
        float4* o4 = (float4*)out + (size_t)node * 64 + cl * 2;
        o4[0] = rv1;
        o4[1] = rv2;
    }
}

// ---------------------------------------------------------------------------
extern "C" void kernel_launch(void* const* d_in, const int* in_sizes, int n_in,
                              void* d_out, int out_size, void* d_ws, size_t ws_size,
                              hipStream_t stream) {
    const float* feat  = (const float*)d_in[0];
    const float* W0    = (const float*)d_in[1];
    const float* W1    = (const float*)d_in[2];
    const float* W2    = (const float*)d_in[3];
    // d_in[4..6] = a0,a1,a2: unused — attention weights are exactly 1/3
    const float* gamma = (const float*)d_in[7];
    const float* beta  = (const float*)d_in[8];
    const int* src0 = (const int*)d_in[9];
    const int* dst0 = (const int*)d_in[10];
    const int* src1 = (const int*)d_in[11];
    const int* dst1 = (const int*)d_in[12];
    const int* src2 = (const int*)d_in[13];
    const int* dst2 = (const int*)d_in[14];
    float* out = (float*)d_out;

    // workspace: h bf16[N*D] | Wt bf16[D*D] | deg[150000] | off[150000] |
    // flag[4] | csum[352] | ghist[351600] | coarse u32[1.2M] | eidx u16[1.2M]
    // total ~35.7 MB
    unsigned short* h  = (unsigned short*)d_ws;
    unsigned short* Wt = h + (size_t)N_NODES * D;
    int* deg    = (int*)(Wt + D * D);
    int* off    = deg + SCAN_N;
    int* flag   = off + SCAN_N;
    int* csum   = flag + 4;
    int* ghist  = csum + 352;
    unsigned int*   coarse = (unsigned int*)(ghist + GHN);
    unsigned short* eidx   = (unsigned short*)(coarse + 3 * E_EDGES);

    k_prep2<<<256 + NBA, 256, 0, stream>>>(W0, W1, W2, Wt, flag,
                                           dst0, dst1, dst2, ghist);
    k_scan_gemm<<<GH_NB + GEMM_NB, 256, 0, stream>>>(ghist, csum, flag, feat, Wt, h);
    k_scatter<<<NBA, 256, 0, stream>>>(src0, dst0, src1, dst1, src2, dst2,
                                       ghist, csum, coarse);
    k_fine<<<NCB, 256, 0, stream>>>(coarse, ghist, csum, deg, off, eidx);
    k_gather<<<(N_NODES + 3) / 4, 256, 0, stream>>>(h, eidx, off, deg,
                                                    gamma, beta, out);
}